// Round 1
// baseline (1210.551 us; speedup 1.0000x reference)
//
#include <hip/hip_runtime.h>
#include <stdint.h>

#define N_NODES 100000
#define N_EDGES 3200000
#define IN_DIM 128
#define HID 64
#define N_GRAPHS 64
#define BN_EPS 1e-5f
#define NSHARD 16
#define SCAN_CHUNK 1024
#define NBLK_SCAN ((N_NODES + SCAN_CHUNK - 1) / SCAN_CHUNK)   // 98

// ---------------------------------------------------------------------------
// degree (weighted, by col) + histogram (edge count per col)
__global__ void k_deg_hist(const int* __restrict__ ei, const float* __restrict__ w,
                           float* __restrict__ deg, int* __restrict__ cnt) {
    int stride = gridDim.x * blockDim.x;
    for (int e = blockIdx.x * blockDim.x + threadIdx.x; e < N_EDGES; e += stride) {
        int c = ei[N_EDGES + e];
        atomicAdd(&deg[c], w[e]);
        atomicAdd(&cnt[c], 1);
    }
}

// dinv = rsqrt(deg + 1)  (the +1 is the self-loop weight)
__global__ void k_dinv(float* __restrict__ dinv) {
    int i = blockIdx.x * blockDim.x + threadIdx.x;
    if (i < N_NODES) dinv[i] = rsqrtf(dinv[i] + 1.0f);
}

// ---------------------------------------------------------------------------
// 3-phase exclusive scan of cnt -> ptr
__global__ void k_scan_local(const int* __restrict__ cnt, int* __restrict__ ptr,
                             int* __restrict__ part) {
    __shared__ int sdata[256];
    int b = blockIdx.x, t = threadIdx.x;
    int base = b * SCAN_CHUNK;
    int v[4];
    int s = 0;
#pragma unroll
    for (int i = 0; i < 4; ++i) {
        int idx = base + t * 4 + i;
        v[i] = s;
        int c = (idx < N_NODES) ? cnt[idx] : 0;
        s += c;
    }
    sdata[t] = s;
    __syncthreads();
    for (int off = 1; off < 256; off <<= 1) {
        int x = (t >= off) ? sdata[t - off] : 0;
        __syncthreads();
        sdata[t] += x;
        __syncthreads();
    }
    int texcl = (t > 0) ? sdata[t - 1] : 0;
#pragma unroll
    for (int i = 0; i < 4; ++i) {
        int idx = base + t * 4 + i;
        if (idx < N_NODES) ptr[idx] = texcl + v[i];
    }
    if (t == 255) part[b] = sdata[255];
}

__global__ void k_scan_part(const int* __restrict__ part, int* __restrict__ offs) {
    __shared__ int sp[128];
    int t = threadIdx.x;   // 128 threads
    sp[t] = (t < NBLK_SCAN) ? part[t] : 0;
    __syncthreads();
    for (int off = 1; off < 128; off <<= 1) {
        int x = (t >= off) ? sp[t - off] : 0;
        __syncthreads();
        sp[t] += x;
        __syncthreads();
    }
    if (t < NBLK_SCAN) offs[t] = (t > 0) ? sp[t - 1] : 0;
}

__global__ void k_scan_add(int* __restrict__ ptr, const int* __restrict__ offs) {
    int i = blockIdx.x * blockDim.x + threadIdx.x;
    if (i < N_NODES) ptr[i] += offs[i >> 10];
}

// ---------------------------------------------------------------------------
// bucket scatter: rows_s / norm_s sorted by destination node; ptr becomes bucket END
__global__ void k_scatter(const int* __restrict__ ei, const float* __restrict__ w,
                          const float* __restrict__ dinv, int* __restrict__ ptr,
                          int* __restrict__ rows_s, float* __restrict__ norm_s) {
    int stride = gridDim.x * blockDim.x;
    for (int e = blockIdx.x * blockDim.x + threadIdx.x; e < N_EDGES; e += stride) {
        int r = ei[e];
        int c = ei[N_EDGES + e];
        float nm = dinv[r] * w[e] * dinv[c];
        int p = atomicAdd(&ptr[c], 1);
        rows_s[p] = r;
        norm_s[p] = nm;
    }
}

// ---------------------------------------------------------------------------
// GEMM: out[n][c] = sum_k in_t[n][k] * W[k][c], optionally in = relu(scale*in+shift)
// block = 256 threads, tile = 128 nodes x 64 channels, thread = 8 nodes x 4 ch
template <int K, bool BN>
__global__ __launch_bounds__(256) void k_gemm(const float* __restrict__ in,
                                              const float* __restrict__ W,
                                              const float* __restrict__ scale,
                                              const float* __restrict__ shift,
                                              float* __restrict__ out) {
    __shared__ float ws[K * 64];
    __shared__ float xs[32 * 132];   // [k_local][node_local], pad 4
    __shared__ float ssc[64], ssh[64];
    int t = threadIdx.x;
    int nbase = blockIdx.x * 128;

    // stage W (flat float4 copy)
#pragma unroll
    for (int i = 0; i < K / 16; ++i) {
        int idx = t + 256 * i;
        ((float4*)ws)[idx] = ((const float4*)W)[idx];
    }
    if (BN && t < 64) { ssc[t] = scale[t]; ssh[t] = shift[t]; }

    int cg = t & 15;   // channel group: channels cg*4 .. cg*4+3
    int ng = t >> 4;   // node group: nodes ng*8 .. ng*8+7
    float acc[8][4];
#pragma unroll
    for (int i = 0; i < 8; ++i)
#pragma unroll
        for (int j = 0; j < 4; ++j) acc[i][j] = 0.f;

    for (int k0 = 0; k0 < K; k0 += 32) {
        __syncthreads();   // protect xs reuse (and W/ssc on first iter)
        // stage transposed x tile: 128 rows x 32 k
#pragma unroll
        for (int i = 0; i < 4; ++i) {
            int idx = t + 256 * i;
            int row = idx >> 3;
            int kq = idx & 7;
            int node = nbase + row;
            float4 v = make_float4(0.f, 0.f, 0.f, 0.f);
            if (node < N_NODES)
                v = *(const float4*)(in + (size_t)node * K + k0 + kq * 4);
            float vv[4] = {v.x, v.y, v.z, v.w};
#pragma unroll
            for (int u = 0; u < 4; ++u) {
                float val = vv[u];
                if (BN) {
                    int k = k0 + kq * 4 + u;
                    val = fmaxf(ssc[k] * val + ssh[k], 0.f);
                }
                xs[(kq * 4 + u) * 132 + row] = val;
            }
        }
        __syncthreads();
#pragma unroll
        for (int k = 0; k < 32; ++k) {
            float4 wv = *(const float4*)(ws + (k0 + k) * 64 + cg * 4);
            float4 xa = *(const float4*)(xs + k * 132 + ng * 8);
            float4 xb = *(const float4*)(xs + k * 132 + ng * 8 + 4);
            float xv[8] = {xa.x, xa.y, xa.z, xa.w, xb.x, xb.y, xb.z, xb.w};
            float wvv[4] = {wv.x, wv.y, wv.z, wv.w};
#pragma unroll
            for (int i = 0; i < 8; ++i)
#pragma unroll
                for (int j = 0; j < 4; ++j) acc[i][j] += xv[i] * wvv[j];
        }
    }
#pragma unroll
    for (int i = 0; i < 8; ++i) {
        int node = nbase + ng * 8 + i;
        if (node < N_NODES) {
            float4 o4 = make_float4(acc[i][0], acc[i][1], acc[i][2], acc[i][3]);
            *(float4*)(out + (size_t)node * 64 + cg * 4) = o4;
        }
    }
}

// ---------------------------------------------------------------------------
// aggregation: hout[v] = sum_{e in bucket(v)} norm_e * hin[row_e] + dinv^2 * hin[v] + bias
// one wave per node (lane = channel), 8 nodes per wave; fused BN sum/sumsq partials
__global__ __launch_bounds__(256) void k_agg(const float* __restrict__ hin,
                                             const int* __restrict__ rows_s,
                                             const float* __restrict__ norm_s,
                                             const int* __restrict__ ptr_end,
                                             const int* __restrict__ cnt,
                                             const float* __restrict__ dinv,
                                             const float* __restrict__ bias,
                                             float* __restrict__ hout,
                                             float* __restrict__ bn_shard) {
    int wave = threadIdx.x >> 6;
    int lane = threadIdx.x & 63;
    float s = 0.f, q = 0.f;
    float bl = bias[lane];
    int vbase = blockIdx.x * 32 + wave * 8;
    for (int vi = 0; vi < 8; ++vi) {
        int v = vbase + vi;
        if (v >= N_NODES) break;
        int end = ptr_end[v];
        int beg = end - cnt[v];
        float acc = 0.f;
        for (int j0 = beg; j0 < end; j0 += 64) {
            int rl = 0;
            float nl = 0.f;
            int jend = min(64, end - j0);
            if (j0 + lane < end) {
                rl = rows_s[j0 + lane];
                nl = norm_s[j0 + lane];
            }
            for (int jj = 0; jj < jend; ++jj) {
                int r = __shfl(rl, jj);
                float nm = __shfl(nl, jj);
                acc += nm * hin[(size_t)r * 64 + lane];
            }
        }
        float dv = dinv[v];
        acc += dv * dv * hin[(size_t)v * 64 + lane];
        acc += bl;
        hout[(size_t)v * 64 + lane] = acc;
        s += acc;
        q += acc * acc;
    }
    __shared__ float sm[4][64], qm[4][64];
    sm[wave][lane] = s;
    qm[wave][lane] = q;
    __syncthreads();
    if (wave == 0) {
        float ts = sm[0][lane] + sm[1][lane] + sm[2][lane] + sm[3][lane];
        float tq = qm[0][lane] + qm[1][lane] + qm[2][lane] + qm[3][lane];
        float* shard = bn_shard + (blockIdx.x & (NSHARD - 1)) * 128;
        atomicAdd(&shard[lane], ts);
        atomicAdd(&shard[64 + lane], tq);
    }
}

// reduce BN shards -> scale/shift; re-zero shards for the next layer
__global__ void k_bn_final(float* __restrict__ bn_shard, const float* __restrict__ gamma,
                           const float* __restrict__ beta, float* __restrict__ scale,
                           float* __restrict__ shift) {
    int t = threadIdx.x;   // 256
    if (t < 64) {
        float s = 0.f, q = 0.f;
        for (int i = 0; i < NSHARD; ++i) {
            s += bn_shard[i * 128 + t];
            q += bn_shard[i * 128 + 64 + t];
        }
        float mean = s * (1.0f / N_NODES);
        float var = q * (1.0f / N_NODES) - mean * mean;
        float sc = gamma[t] * rsqrtf(var + BN_EPS);
        scale[t] = sc;
        shift[t] = beta[t] - mean * sc;
    }
    __syncthreads();
    for (int i = t; i < NSHARD * 128; i += 256) bn_shard[i] = 0.f;
}

// ---------------------------------------------------------------------------
// pool: h2 = relu(scale2*a2+shift2); per-graph sums + counts (batch is sorted)
__global__ __launch_bounds__(256) void k_pool(const float* __restrict__ a2,
                                              const float* __restrict__ scale,
                                              const float* __restrict__ shift,
                                              const int* __restrict__ batch,
                                              float* __restrict__ pooled,
                                              float* __restrict__ pcnt) {
    int t = threadIdx.x;
    int c = t & 63;
    int rg = t >> 6;   // 0..3
    int base = blockIdx.x * 1024;
    float sc = scale[c], sh = shift[c];
    int gcur = -1;
    float acc = 0.f, cacc = 0.f;
    for (int i = rg; i < 1024; i += 4) {
        int v = base + i;
        if (v >= N_NODES) break;
        int g = batch[v];
        if (g != gcur) {
            if (gcur >= 0) {
                atomicAdd(&pooled[gcur * 64 + c], acc);
                if (c == 0) atomicAdd(&pcnt[gcur], cacc);
            }
            gcur = g;
            acc = 0.f;
            cacc = 0.f;
        }
        float h = fmaxf(sc * a2[(size_t)v * 64 + c] + sh, 0.f);
        acc += h;
        cacc += 1.f;
    }
    if (gcur >= 0) {
        atomicAdd(&pooled[gcur * 64 + c], acc);
        if (c == 0) atomicAdd(&pcnt[gcur], cacc);
    }
}

__global__ void k_out(const float* __restrict__ pooled, const float* __restrict__ pcnt,
                      const float* __restrict__ Wout, const float* __restrict__ bout,
                      float* __restrict__ out) {
    int g = threadIdx.x;
    if (g < N_GRAPHS) {
        float cnt = fmaxf(pcnt[g], 1.0f);
        float s = 0.f;
        for (int c = 0; c < 64; ++c) s += pooled[g * 64 + c] * Wout[c];
        out[g] = s / cnt + bout[0];
    }
}

// ---------------------------------------------------------------------------
extern "C" void kernel_launch(void* const* d_in, const int* in_sizes, int n_in,
                              void* d_out, int out_size, void* d_ws, size_t ws_size,
                              hipStream_t stream) {
    const float* x    = (const float*)d_in[0];
    const int*   ei   = (const int*)d_in[1];    // [2, E] int32
    const float* ew   = (const float*)d_in[2];
    const int*   batch= (const int*)d_in[3];
    const float* W1   = (const float*)d_in[4];
    const float* b1   = (const float*)d_in[5];
    const float* W2   = (const float*)d_in[6];
    const float* b2   = (const float*)d_in[7];
    const float* g1   = (const float*)d_in[8];
    const float* be1  = (const float*)d_in[9];
    const float* g2   = (const float*)d_in[10];
    const float* be2  = (const float*)d_in[11];
    const float* Wout = (const float*)d_in[12];
    const float* bout = (const float*)d_in[13];
    float* out = (float*)d_out;

    // workspace carve-up
    char* w = (char*)d_ws;
    size_t o = 0;
    auto alloc = [&](size_t bytes) -> void* {
        void* p = w + o;
        o = (o + bytes + 255) & ~(size_t)255;
        return p;
    };
    float* dinv    = (float*)alloc(N_NODES * 4);
    int*   cnt     = (int*)alloc(N_NODES * 4);
    int*   ptr     = (int*)alloc(N_NODES * 4);
    int*   part    = (int*)alloc(512);
    int*   offs    = (int*)alloc(512);
    float* bnshard = (float*)alloc(NSHARD * 128 * 4);
    float* scale1  = (float*)alloc(64 * 4);
    float* shift1  = (float*)alloc(64 * 4);
    float* scale2  = (float*)alloc(64 * 4);
    float* shift2  = (float*)alloc(64 * 4);
    float* pooled  = (float*)alloc(N_GRAPHS * 64 * 4);
    float* pcnt    = (float*)alloc(N_GRAPHS * 4);
    int*   rows_s  = (int*)alloc((size_t)N_EDGES * 4);
    float* norm_s  = (float*)alloc((size_t)N_EDGES * 4);
    float* bufA    = (float*)alloc((size_t)N_NODES * 64 * 4);
    float* bufB    = (float*)alloc((size_t)N_NODES * 64 * 4);
    if (o > ws_size) return;   // workspace too small -> fail loudly at validation

    hipMemsetAsync(dinv, 0, N_NODES * 4, stream);
    hipMemsetAsync(cnt, 0, N_NODES * 4, stream);
    hipMemsetAsync(bnshard, 0, NSHARD * 128 * 4, stream);
    hipMemsetAsync(pooled, 0, N_GRAPHS * 64 * 4, stream);
    hipMemsetAsync(pcnt, 0, N_GRAPHS * 4, stream);

    k_deg_hist<<<3125, 256, 0, stream>>>(ei, ew, dinv, cnt);
    k_dinv<<<(N_NODES + 255) / 256, 256, 0, stream>>>(dinv);
    k_scan_local<<<NBLK_SCAN, 256, 0, stream>>>(cnt, ptr, part);
    k_scan_part<<<1, 128, 0, stream>>>(part, offs);
    k_scan_add<<<(N_NODES + 255) / 256, 256, 0, stream>>>(ptr, offs);
    k_scatter<<<3125, 256, 0, stream>>>(ei, ew, dinv, ptr, rows_s, norm_s);

    // layer 1
    k_gemm<128, false><<<(N_NODES + 127) / 128, 256, 0, stream>>>(x, W1, nullptr, nullptr, bufA);
    k_agg<<<(N_NODES + 31) / 32, 256, 0, stream>>>(bufA, rows_s, norm_s, ptr, cnt, dinv, b1, bufB, bnshard);
    k_bn_final<<<1, 256, 0, stream>>>(bnshard, g1, be1, scale1, shift1);

    // layer 2
    k_gemm<64, true><<<(N_NODES + 127) / 128, 256, 0, stream>>>(bufB, W2, scale1, shift1, bufA);
    k_agg<<<(N_NODES + 31) / 32, 256, 0, stream>>>(bufA, rows_s, norm_s, ptr, cnt, dinv, b2, bufB, bnshard);
    k_bn_final<<<1, 256, 0, stream>>>(bnshard, g2, be2, scale2, shift2);

    // pool + output
    k_pool<<<(N_NODES + 1023) / 1024, 256, 0, stream>>>(bufB, scale2, shift2, batch, pooled, pcnt);
    k_out<<<1, 64, 0, stream>>>(pooled, pcnt, Wout, bout, out);
}